// Round 4
// baseline (957.650 us; speedup 1.0000x reference)
//
#include <hip/hip_runtime.h>
#include <hip/hip_bf16.h>
#include <cstdint>

typedef float f4  __attribute__((ext_vector_type(4)));
typedef short s8v __attribute__((ext_vector_type(8)));   // 8 bf16 (4 VGPRs)
typedef int   i4v __attribute__((ext_vector_type(4)));

#define BHTD 3145728    // B*H*T*D = 2*12*2048*64
#define BTC  3145728
#define NT   2048
#define NC   768
#define NEG  -1e30f

static __device__ __forceinline__ short bfbits(float f) {
    return __builtin_bit_cast(short, __float2bfloat16(f));
}
static __device__ __forceinline__ float bf2f(short s) {
    return __builtin_bit_cast(float, (int)(((unsigned int)(unsigned short)s) << 16));
}
template <int ctrl>
static __device__ __forceinline__ float dppmov(float x) {
    return __builtin_bit_cast(float,
        __builtin_amdgcn_update_dpp(0, __builtin_bit_cast(int, x), ctrl, 0xF, 0xF, true));
}
// reductions over the 16 lanes of a DPP row
static __device__ __forceinline__ float red16max(float x) {
    x = fmaxf(x, dppmov<0xB1>(x));    // quad_perm xor1
    x = fmaxf(x, dppmov<0x4E>(x));    // quad_perm xor2
    x = fmaxf(x, dppmov<0x141>(x));   // row_half_mirror (xor4)
    x = fmaxf(x, dppmov<0x140>(x));   // row_mirror      (xor8)
    return x;
}
static __device__ __forceinline__ float red16sum(float x) {
    x += dppmov<0xB1>(x);
    x += dppmov<0x4E>(x);
    x += dppmov<0x141>(x);
    x += dppmov<0x140>(x);
    return x;
}

// ---------------------------------------------------------------------------
// Kernel 1: MFMA QKV projection. nom=x@W^T, mid=m@W^T, rad=r@|W|^T (bf16 in,
// fp32 acc). Outputs bf16: Q,K in [var][part][B,H,T,D]; V in [B,H,D,T]
// (transposed at producer so flash needs no LDS transpose / staging).
// ---------------------------------------------------------------------------
__global__ __launch_bounds__(256) void qkv_proj_mfma(
    const float* __restrict__ x, const float* __restrict__ xl,
    const float* __restrict__ xu, const float* __restrict__ W,
    short* __restrict__ qkvb)
{
    __shared__ short sm[4 * 64 * 40];   // 20 KB staging; epilogue reuses as [64][72]
    short* Ax = sm;
    short* Am = sm + 2560;
    short* Ar = sm + 5120;
    short* Bw = sm + 7680;
    short* Eb = sm;                     // epilogue [64][72]

    const int j0 = blockIdx.x * 64;     // N in [0,2304)
    const int n0 = blockIdx.y * 64;     // M in [0,4096)
    const int t  = threadIdx.x;
    const int wv = t >> 6, lane = t & 63, quad = lane >> 4, l16 = lane & 15;
    const int rw = t >> 2, koff = (t & 3) * 8;

    f4 aN[4], aM[4], aR[4];
#pragma unroll
    for (int i = 0; i < 4; i++) { aN[i] = f4{0,0,0,0}; aM[i] = f4{0,0,0,0}; aR[i] = f4{0,0,0,0}; }

    for (int k0 = 0; k0 < NC; k0 += 32) {
        const size_t xo = (size_t)(n0 + rw) * NC + k0 + koff;
        const f4 x0 = *(const f4*)&x[xo],  x1 = *(const f4*)&x[xo + 4];
        const f4 l0 = *(const f4*)&xl[xo], l1 = *(const f4*)&xl[xo + 4];
        const f4 u0 = *(const f4*)&xu[xo], u1 = *(const f4*)&xu[xo + 4];
        const size_t wo = (size_t)(j0 + rw) * NC + k0 + koff;
        const f4 w0 = *(const f4*)&W[wo], w1 = *(const f4*)&W[wo + 4];
        s8v vx, vm, vr, vw;
#pragma unroll
        for (int i = 0; i < 4; i++) {
            vx[i]     = bfbits(x0[i]);              vx[4 + i] = bfbits(x1[i]);
            vm[i]     = bfbits(0.5f * (l0[i] + u0[i])); vm[4 + i] = bfbits(0.5f * (l1[i] + u1[i]));
            vr[i]     = bfbits(0.5f * (u0[i] - l0[i])); vr[4 + i] = bfbits(0.5f * (u1[i] - l1[i]));
            vw[i]     = bfbits(w0[i]);              vw[4 + i] = bfbits(w1[i]);
        }
        __syncthreads();
        *(s8v*)&Ax[rw * 40 + koff] = vx;
        *(s8v*)&Am[rw * 40 + koff] = vm;
        *(s8v*)&Ar[rw * 40 + koff] = vr;
        *(s8v*)&Bw[rw * 40 + koff] = vw;
        __syncthreads();
        const s8v fx = *(const s8v*)&Ax[(wv * 16 + l16) * 40 + quad * 8];
        const s8v fm = *(const s8v*)&Am[(wv * 16 + l16) * 40 + quad * 8];
        const s8v fr = *(const s8v*)&Ar[(wv * 16 + l16) * 40 + quad * 8];
#pragma unroll
        for (int nt = 0; nt < 4; ++nt) {
            const s8v fb = *(const s8v*)&Bw[(nt * 16 + l16) * 40 + quad * 8];
            i4v bi = __builtin_bit_cast(i4v, fb);
#pragma unroll
            for (int i = 0; i < 4; i++) bi[i] &= 0x7fff7fff;
            const s8v fa = __builtin_bit_cast(s8v, bi);
            aN[nt] = __builtin_amdgcn_mfma_f32_16x16x32_bf16(fx, fb, aN[nt], 0, 0, 0);
            aM[nt] = __builtin_amdgcn_mfma_f32_16x16x32_bf16(fm, fb, aM[nt], 0, 0, 0);
            aR[nt] = __builtin_amdgcn_mfma_f32_16x16x32_bf16(fr, fa, aR[nt], 0, 0, 0);
        }
    }

    const int p = j0 / NC, hh = (j0 % NC) >> 6;
    const int cc16 = (t & 3) * 16;
    for (int var = 0; var < 3; ++var) {
        __syncthreads();
#pragma unroll
        for (int nt = 0; nt < 4; ++nt)
#pragma unroll
            for (int r = 0; r < 4; ++r) {
                const float v = (var == 0) ? aN[nt][r]
                              : (var == 1) ? aM[nt][r] - aR[nt][r]
                                           : aM[nt][r] + aR[nt][r];
                Eb[(wv * 16 + quad * 4 + r) * 72 + nt * 16 + l16] = bfbits(v);
            }
        __syncthreads();
        short* dst = qkvb + (size_t)(var * 3 + p) * BHTD;
        if (p < 2) {       // Q,K row-major [B,H,T,D]
            const int token = n0 + rw, b = token >> 11, tt = token & 2047;
            const size_t o = ((size_t)(b * 12 + hh) * NT + tt) * 64 + cc16;
            *(s8v*)&dst[o]     = *(const s8v*)&Eb[rw * 72 + cc16];
            *(s8v*)&dst[o + 8] = *(const s8v*)&Eb[rw * 72 + cc16 + 8];
        } else {           // V transposed [B,H,D,T]
            const int d = rw;
            s8v e0, e1;
#pragma unroll
            for (int i = 0; i < 8; i++) e0[i] = Eb[(cc16 + i) * 72 + d];
#pragma unroll
            for (int i = 0; i < 8; i++) e1[i] = Eb[(cc16 + 8 + i) * 72 + d];
            const int token0 = n0 + cc16, b = token0 >> 11, tt = token0 & 2047;
            const size_t o = ((size_t)(b * 12 + hh) * 64 + d) * NT + tt;
            *(s8v*)&dst[o]     = e0;
            *(s8v*)&dst[o + 8] = e1;
        }
    }
}

// ---------------------------------------------------------------------------
// Kernel 2: barrier-free MFMA flash. grid.z = sv in 0..4.
//   sv0: (qn,kn)x{vn} -> y fp32; sv1..4: (q lo/hi,k lo/hi)x{vlo,vhi} -> cand bf16
// Block = 128 q-rows, 4 independent waves x 32 rows. NO __syncthreads:
// K/V fragments are direct global b128 loads (V is [B,H,D,T]); only P
// round-trips LDS and its rows are wave-private.
// ---------------------------------------------------------------------------
__global__ __launch_bounds__(256) void flash_mfma_all(
    const short* __restrict__ qkvb, float* __restrict__ ybuf,
    short* __restrict__ cand)
{
    const int qt = 15 - (int)blockIdx.x;   // heavy first
    const int bh = blockIdx.y;
    const int sv = blockIdx.z;             // 0..4
    const int q0 = qt * 128;
    const int t  = threadIdx.x;
    const int wv = t >> 6, lane = t & 63, quad = lane >> 4, l16 = lane & 15;

    __shared__ short Ps[128 * 40];         // [qrow][kpos], wave-private rows

    const bool two = (sv > 0);
    const int qvi = (sv + 1) >> 1;
    const int kvi = two ? 2 - (sv & 1) : 0;
    const int v0i = two ? 1 : 0;
    const int v1i = two ? 2 : 0;

    const size_t hb = (size_t)bh * (NT * 64);
    const short* Qp  = qkvb + (size_t)(qvi * 3 + 0) * BHTD + hb;  // [t][d]
    const short* Kp  = qkvb + (size_t)(kvi * 3 + 1) * BHTD + hb;  // [t][d]
    const short* V0p = qkvb + (size_t)(v0i * 3 + 2) * BHTD + hb;  // [d][t]
    const short* V1p = qkvb + (size_t)(v1i * 3 + 2) * BHTD + hb;  // [d][t]

    s8v qf[2][2];
#pragma unroll
    for (int mt = 0; mt < 2; ++mt)
#pragma unroll
        for (int ch = 0; ch < 2; ++ch)
            qf[mt][ch] = *(const s8v*)&Qp[(size_t)(q0 + 32 * wv + 16 * mt + l16) * 64 + ch * 32 + quad * 8];

    float mi[2][4], li[2][4];
    f4 acc0[2][4], acc1[2][4];
#pragma unroll
    for (int mt = 0; mt < 2; ++mt)
#pragma unroll
        for (int r = 0; r < 4; ++r) { mi[mt][r] = NEG; li[mt][r] = 0.f; }
#pragma unroll
    for (int mt = 0; mt < 2; ++mt)
#pragma unroll
        for (int i = 0; i < 4; ++i) { acc0[mt][i] = f4{0,0,0,0}; acc1[mt][i] = f4{0,0,0,0}; }

    const int myktn = 4 * qt + wv + 1;     // causal bound for THIS wave's rows

    for (int kt = 0; kt < myktn; ++kt) {
        const int k0 = kt * 32;

        // ---- K fragments: direct global b128 ----
        s8v kf[2][2];
#pragma unroll
        for (int nt = 0; nt < 2; ++nt)
#pragma unroll
            for (int ch = 0; ch < 2; ++ch)
                kf[nt][ch] = *(const s8v*)&Kp[(size_t)(k0 + nt * 16 + l16) * 64 + ch * 32 + quad * 8];

        // ---- S = Q K^T ----
        f4 s[2][2];
#pragma unroll
        for (int mt = 0; mt < 2; ++mt) { s[mt][0] = f4{0,0,0,0}; s[mt][1] = f4{0,0,0,0}; }
#pragma unroll
        for (int nt = 0; nt < 2; ++nt)
#pragma unroll
            for (int ch = 0; ch < 2; ++ch) {
                s[0][nt] = __builtin_amdgcn_mfma_f32_16x16x32_bf16(qf[0][ch], kf[nt][ch], s[0][nt], 0, 0, 0);
                s[1][nt] = __builtin_amdgcn_mfma_f32_16x16x32_bf16(qf[1][ch], kf[nt][ch], s[1][nt], 0, 0, 0);
            }

        // ---- V fragments: issue early so latency overlaps softmax ----
        s8v vf0[4], vf1[4];
#pragma unroll
        for (int dt = 0; dt < 4; ++dt)
            vf0[dt] = *(const s8v*)&V0p[(size_t)(dt * 16 + l16) * NT + k0 + quad * 8];
        if (two) {
#pragma unroll
            for (int dt = 0; dt < 4; ++dt)
                vf1[dt] = *(const s8v*)&V1p[(size_t)(dt * 16 + l16) * NT + k0 + quad * 8];
        }

        // ---- softmax per m-tile ----
#pragma unroll
        for (int mt = 0; mt < 2; ++mt) {
            const int rowb = q0 + 32 * wv + 16 * mt;
            float a0[4], a1[4];
#pragma unroll
            for (int r = 0; r < 4; ++r) { a0[r] = s[mt][0][r] * 0.125f; a1[r] = s[mt][1][r] * 0.125f; }
            if (k0 + 31 > rowb) {
#pragma unroll
                for (int r = 0; r < 4; ++r) {
                    const int row = rowb + quad * 4 + r;
                    if (k0 + l16 > row)      a0[r] = NEG;
                    if (k0 + 16 + l16 > row) a1[r] = NEG;
                }
            }
#pragma unroll
            for (int r = 0; r < 4; ++r) {
                const float mx = red16max(fmaxf(a0[r], a1[r]));
                const float nm = fmaxf(mi[mt][r], mx);
                const float al = __expf(mi[mt][r] - nm);
                a0[r] = __expf(a0[r] - nm);
                a1[r] = __expf(a1[r] - nm);
                mi[mt][r] = nm;
                const float rs = red16sum(a0[r] + a1[r]);
                li[mt][r] = li[mt][r] * al + rs;
                Ps[(32 * wv + 16 * mt + quad * 4 + r) * 40 + l16]      = bfbits(a0[r]);
                Ps[(32 * wv + 16 * mt + quad * 4 + r) * 40 + 16 + l16] = bfbits(a1[r]);
#pragma unroll
                for (int dt = 0; dt < 4; ++dt) acc0[mt][dt][r] *= al;
                if (two) {
#pragma unroll
                    for (int dt = 0; dt < 4; ++dt) acc1[mt][dt][r] *= al;
                }
            }
        }

        // ---- O += P V (P via LDS, wave-private rows: no barrier) ----
        const s8v pf0 = *(const s8v*)&Ps[(32 * wv + l16) * 40 + quad * 8];
        const s8v pf1 = *(const s8v*)&Ps[(32 * wv + 16 + l16) * 40 + quad * 8];
#pragma unroll
        for (int dt = 0; dt < 4; ++dt) {
            acc0[0][dt] = __builtin_amdgcn_mfma_f32_16x16x32_bf16(pf0, vf0[dt], acc0[0][dt], 0, 0, 0);
            acc0[1][dt] = __builtin_amdgcn_mfma_f32_16x16x32_bf16(pf1, vf0[dt], acc0[1][dt], 0, 0, 0);
            if (two) {
                acc1[0][dt] = __builtin_amdgcn_mfma_f32_16x16x32_bf16(pf0, vf1[dt], acc1[0][dt], 0, 0, 0);
                acc1[1][dt] = __builtin_amdgcn_mfma_f32_16x16x32_bf16(pf1, vf1[dt], acc1[1][dt], 0, 0, 0);
            }
        }
    }

#pragma unroll
    for (int mt = 0; mt < 2; ++mt) {
        float inv[4];
#pragma unroll
        for (int r = 0; r < 4; ++r) inv[r] = 1.f / li[mt][r];
#pragma unroll
        for (int dt = 0; dt < 4; ++dt)
#pragma unroll
            for (int r = 0; r < 4; ++r) {
                const size_t o = hb + (size_t)(q0 + 32 * wv + 16 * mt + quad * 4 + r) * 64 + dt * 16 + l16;
                if (!two) {
                    ybuf[o] = acc0[mt][dt][r] * inv[r];
                } else {
                    const float xa = acc0[mt][dt][r] * inv[r];
                    const float xb = acc1[mt][dt][r] * inv[r];
                    cand[(size_t)(sv - 1) * BHTD + o] = bfbits(fminf(xa, xb));
                    cand[(size_t)(3 + sv) * BHTD + o] = bfbits(fmaxf(xa, xb));
                }
            }
    }
}

// ---------------------------------------------------------------------------
// Kernel 3: MFMA output projection. z=0: A=y fp32; z=1: A=min of 4 candLo;
// z=2: A=max of 4 candHi. B=Wp (bf16). out fp32 via LDS re-layout.
// ---------------------------------------------------------------------------
__global__ __launch_bounds__(256) void out_proj_mfma(
    const float* __restrict__ ybuf, const short* __restrict__ cand,
    const float* __restrict__ Wp, float* __restrict__ out)
{
    __shared__ float smf[64 * 68];          // 17.4 KB; staging aliases first 10.2 KB
    short* As = (short*)smf;                // [64][40]
    short* Bs = As + 2560;
    float* Eb = smf;                        // [64][68]

    const int o  = blockIdx.z;
    const int j0 = blockIdx.x * 64, n0 = blockIdx.y * 64;
    const int t  = threadIdx.x;
    const int wv = t >> 6, lane = t & 63, quad = lane >> 4, l16 = lane & 15;
    const int rw = t >> 2, koff = (t & 3) * 8;

    f4 acc[4];
#pragma unroll
    for (int i = 0; i < 4; i++) acc[i] = f4{0,0,0,0};

    const int token = n0 + rw, b = token >> 11, tt = token & 2047;

    for (int k0 = 0; k0 < NC; k0 += 32) {
        const int hh = k0 >> 6, d0 = (k0 & 63) + koff;
        const size_t aoff = ((size_t)(b * 12 + hh) * NT + tt) * 64 + d0;
        s8v av;
        if (o == 0) {
            const f4 y0 = *(const f4*)&ybuf[aoff];
            const f4 y1 = *(const f4*)&ybuf[aoff + 4];
#pragma unroll
            for (int i = 0; i < 4; i++) { av[i] = bfbits(y0[i]); av[4 + i] = bfbits(y1[i]); }
        } else {
            const short* cb = cand + (size_t)(o == 1 ? 0 : 4) * BHTD;
            float v[8];
            {
                const s8v c0 = *(const s8v*)&cb[aoff];
#pragma unroll
                for (int i = 0; i < 8; i++) v[i] = bf2f(c0[i]);
            }
#pragma unroll
            for (int q = 1; q < 4; ++q) {
                const s8v cq = *(const s8v*)&cb[(size_t)q * BHTD + aoff];
                if (o == 1) {
#pragma unroll
                    for (int i = 0; i < 8; i++) v[i] = fminf(v[i], bf2f(cq[i]));
                } else {
#pragma unroll
                    for (int i = 0; i < 8; i++) v[i] = fmaxf(v[i], bf2f(cq[i]));
                }
            }
#pragma unroll
            for (int i = 0; i < 8; i++) av[i] = bfbits(v[i]);
        }
        const size_t wo = (size_t)(j0 + rw) * NC + k0 + koff;
        const f4 w0 = *(const f4*)&Wp[wo], w1 = *(const f4*)&Wp[wo + 4];
        s8v bv;
#pragma unroll
        for (int i = 0; i < 4; i++) { bv[i] = bfbits(w0[i]); bv[4 + i] = bfbits(w1[i]); }
        __syncthreads();
        *(s8v*)&As[rw * 40 + koff] = av;
        *(s8v*)&Bs[rw * 40 + koff] = bv;
        __syncthreads();
        const s8v af = *(const s8v*)&As[(wv * 16 + l16) * 40 + quad * 8];
#pragma unroll
        for (int nt = 0; nt < 4; ++nt) {
            const s8v bf = *(const s8v*)&Bs[(nt * 16 + l16) * 40 + quad * 8];
            acc[nt] = __builtin_amdgcn_mfma_f32_16x16x32_bf16(af, bf, acc[nt], 0, 0, 0);
        }
    }
    __syncthreads();
#pragma unroll
    for (int nt = 0; nt < 4; ++nt)
#pragma unroll
        for (int r = 0; r < 4; ++r)
            Eb[(wv * 16 + quad * 4 + r) * 68 + nt * 16 + l16] = acc[nt][r];
    __syncthreads();
    const int cc = (t & 3) * 16;
#pragma unroll
    for (int i = 0; i < 4; ++i) {
        const f4 vo = *(const f4*)&Eb[rw * 68 + cc + 4 * i];
        *(f4*)&out[(size_t)o * BTC + (size_t)(n0 + rw) * NC + j0 + cc + 4 * i] = vo;
    }
}

extern "C" void kernel_launch(void* const* d_in, const int* in_sizes, int n_in,
                              void* d_out, int out_size, void* d_ws, size_t ws_size,
                              hipStream_t stream)
{
    const float* x  = (const float*)d_in[0];
    const float* xl = (const float*)d_in[1];
    const float* xu = (const float*)d_in[2];
    const float* Wa = (const float*)d_in[3];
    const float* Wp = (const float*)d_in[4];
    float* out = (float*)d_out;

    short* qkvb = (short*)d_ws;                       // 9*BHTD bf16  = 56.6 MB
    float* ybuf = (float*)(qkvb + (size_t)9 * BHTD);  // 1*BHTD f32   = 12.6 MB
    short* cand = (short*)(ybuf + (size_t)BHTD);      // 8*BHTD bf16  = 50.3 MB

    qkv_proj_mfma <<<dim3(36, 64),    256, 0, stream>>>(x, xl, xu, Wa, qkvb);
    flash_mfma_all<<<dim3(16, 24, 5), 256, 0, stream>>>(qkvb, ybuf, cand);
    out_proj_mfma <<<dim3(12, 64, 3), 256, 0, stream>>>(ybuf, cand, Wp, out);
}

// Round 6
// 916.927 us; speedup vs baseline: 1.0444x; 1.0444x over previous
//
#include <hip/hip_runtime.h>
#include <hip/hip_bf16.h>
#include <cstdint>

typedef float f4  __attribute__((ext_vector_type(4)));
typedef short s8v __attribute__((ext_vector_type(8)));   // 8 bf16 (4 VGPRs)
typedef int   i4v __attribute__((ext_vector_type(4)));

#define BHTD 3145728    // B*H*T*D = 2*12*2048*64
#define BTC  3145728
#define NT   2048
#define NC   768
#define NEG  -1e30f
// fixed-shift softmax: p = exp(s - 20) = 2^(s*log2e - 20*log2e)
#define EXC1 1.4426950408889634f
#define EXC0 -28.853900817779268f

static __device__ __forceinline__ short bfbits(float f) {
    return __builtin_bit_cast(short, __float2bfloat16(f));
}
static __device__ __forceinline__ float bf2f(short s) {
    return __builtin_bit_cast(float, (int)(((unsigned int)(unsigned short)s) << 16));
}
static __device__ __forceinline__ float fast_exp2(float x) {
    return __builtin_amdgcn_exp2f(x);    // v_exp_f32 (D = 2^S0)
}
template <int ctrl>
static __device__ __forceinline__ float dppmov(float x) {
    return __builtin_bit_cast(float,
        __builtin_amdgcn_update_dpp(0, __builtin_bit_cast(int, x), ctrl, 0xF, 0xF, true));
}
static __device__ __forceinline__ float red16sum(float x) {
    x += dppmov<0xB1>(x);     // quad_perm xor1
    x += dppmov<0x4E>(x);     // quad_perm xor2
    x += dppmov<0x141>(x);    // row_half_mirror (xor4)
    x += dppmov<0x140>(x);    // row_mirror      (xor8)
    return x;
}

// ---------------------------------------------------------------------------
// Kernel 1: MFMA QKV projection. nom=x@W^T, mid=m@W^T, rad=r@|W|^T (bf16 in,
// fp32 acc). Outputs bf16: Q (pre-scaled by 1/8), K in [var][part][B,H,T,D];
// V in [B,H,D,T] (transposed at producer).
// ---------------------------------------------------------------------------
__global__ __launch_bounds__(256) void qkv_proj_mfma(
    const float* __restrict__ x, const float* __restrict__ xl,
    const float* __restrict__ xu, const float* __restrict__ W,
    short* __restrict__ qkvb)
{
    __shared__ short sm[4 * 64 * 40];   // 20 KB staging; epilogue reuses as [64][72]
    short* Ax = sm;
    short* Am = sm + 2560;
    short* Ar = sm + 5120;
    short* Bw = sm + 7680;
    short* Eb = sm;                     // epilogue [64][72]

    const int j0 = blockIdx.x * 64;     // N in [0,2304)
    const int n0 = blockIdx.y * 64;     // M in [0,4096)
    const int t  = threadIdx.x;
    const int wv = t >> 6, lane = t & 63, quad = lane >> 4, l16 = lane & 15;
    const int rw = t >> 2, koff = (t & 3) * 8;

    f4 aN[4], aM[4], aR[4];
#pragma unroll
    for (int i = 0; i < 4; i++) { aN[i] = f4{0,0,0,0}; aM[i] = f4{0,0,0,0}; aR[i] = f4{0,0,0,0}; }

    for (int k0 = 0; k0 < NC; k0 += 32) {
        const size_t xo = (size_t)(n0 + rw) * NC + k0 + koff;
        const f4 x0 = *(const f4*)&x[xo],  x1 = *(const f4*)&x[xo + 4];
        const f4 l0 = *(const f4*)&xl[xo], l1 = *(const f4*)&xl[xo + 4];
        const f4 u0 = *(const f4*)&xu[xo], u1 = *(const f4*)&xu[xo + 4];
        const size_t wo = (size_t)(j0 + rw) * NC + k0 + koff;
        const f4 w0 = *(const f4*)&W[wo], w1 = *(const f4*)&W[wo + 4];
        s8v vx, vm, vr, vw;
#pragma unroll
        for (int i = 0; i < 4; i++) {
            vx[i]     = bfbits(x0[i]);              vx[4 + i] = bfbits(x1[i]);
            vm[i]     = bfbits(0.5f * (l0[i] + u0[i])); vm[4 + i] = bfbits(0.5f * (l1[i] + u1[i]));
            vr[i]     = bfbits(0.5f * (u0[i] - l0[i])); vr[4 + i] = bfbits(0.5f * (u1[i] - l1[i]));
            vw[i]     = bfbits(w0[i]);              vw[4 + i] = bfbits(w1[i]);
        }
        __syncthreads();
        *(s8v*)&Ax[rw * 40 + koff] = vx;
        *(s8v*)&Am[rw * 40 + koff] = vm;
        *(s8v*)&Ar[rw * 40 + koff] = vr;
        *(s8v*)&Bw[rw * 40 + koff] = vw;
        __syncthreads();
        const s8v fx = *(const s8v*)&Ax[(wv * 16 + l16) * 40 + quad * 8];
        const s8v fm = *(const s8v*)&Am[(wv * 16 + l16) * 40 + quad * 8];
        const s8v fr = *(const s8v*)&Ar[(wv * 16 + l16) * 40 + quad * 8];
#pragma unroll
        for (int nt = 0; nt < 4; ++nt) {
            const s8v fb = *(const s8v*)&Bw[(nt * 16 + l16) * 40 + quad * 8];
            i4v bi = __builtin_bit_cast(i4v, fb);
#pragma unroll
            for (int i = 0; i < 4; i++) bi[i] &= 0x7fff7fff;
            const s8v fa = __builtin_bit_cast(s8v, bi);
            aN[nt] = __builtin_amdgcn_mfma_f32_16x16x32_bf16(fx, fb, aN[nt], 0, 0, 0);
            aM[nt] = __builtin_amdgcn_mfma_f32_16x16x32_bf16(fm, fb, aM[nt], 0, 0, 0);
            aR[nt] = __builtin_amdgcn_mfma_f32_16x16x32_bf16(fr, fa, aR[nt], 0, 0, 0);
        }
    }

    const int p = j0 / NC, hh = (j0 % NC) >> 6;
    const float qsc = (p == 0) ? 0.125f : 1.0f;     // fold 1/sqrt(D) into Q
    const int cc16 = (t & 3) * 16;
    for (int var = 0; var < 3; ++var) {
        __syncthreads();
#pragma unroll
        for (int nt = 0; nt < 4; ++nt)
#pragma unroll
            for (int r = 0; r < 4; ++r) {
                const float v = ((var == 0) ? aN[nt][r]
                              : (var == 1) ? aM[nt][r] - aR[nt][r]
                                           : aM[nt][r] + aR[nt][r]) * qsc;
                Eb[(wv * 16 + quad * 4 + r) * 72 + nt * 16 + l16] = bfbits(v);
            }
        __syncthreads();
        short* dst = qkvb + (size_t)(var * 3 + p) * BHTD;
        if (p < 2) {       // Q,K row-major [B,H,T,D]
            const int token = n0 + rw, b = token >> 11, tt = token & 2047;
            const size_t o = ((size_t)(b * 12 + hh) * NT + tt) * 64 + cc16;
            *(s8v*)&dst[o]     = *(const s8v*)&Eb[rw * 72 + cc16];
            *(s8v*)&dst[o + 8] = *(const s8v*)&Eb[rw * 72 + cc16 + 8];
        } else {           // V transposed [B,H,D,T]
            const int d = rw;
            s8v e0, e1;
#pragma unroll
            for (int i = 0; i < 8; i++) e0[i] = Eb[(cc16 + i) * 72 + d];
#pragma unroll
            for (int i = 0; i < 8; i++) e1[i] = Eb[(cc16 + 8 + i) * 72 + d];
            const int token0 = n0 + cc16, b = token0 >> 11, tt = token0 & 2047;
            const size_t o = ((size_t)(b * 12 + hh) * 64 + d) * NT + tt;
            *(s8v*)&dst[o]     = e0;
            *(s8v*)&dst[o + 8] = e1;
        }
    }
}

// ---------------------------------------------------------------------------
// Kernel 2: barrier-free MFMA flash with FIXED-SHIFT softmax (no running max,
// no rescale, deferred l-reduction). grid.z = sv in 0..4.
// Block = 128 q-rows, 4 independent waves x 32 rows. No __syncthreads.
// ---------------------------------------------------------------------------
__global__ __launch_bounds__(256) void flash_mfma_all(
    const short* __restrict__ qkvb, float* __restrict__ ybuf,
    short* __restrict__ cand)
{
    const int qt = 15 - (int)blockIdx.x;   // heavy first
    const int bh = blockIdx.y;
    const int sv = blockIdx.z;             // 0..4
    const int q0 = qt * 128;
    const int t  = threadIdx.x;
    const int wv = t >> 6, lane = t & 63, quad = lane >> 4, l16 = lane & 15;

    __shared__ short Ps[128 * 40];         // [qrow][kpos], wave-private rows

    const bool two = (sv > 0);
    const int qvi = (sv + 1) >> 1;
    const int kvi = two ? 2 - (sv & 1) : 0;
    const int v0i = two ? 1 : 0;
    const int v1i = two ? 2 : 0;

    const size_t hb = (size_t)bh * (NT * 64);
    const short* Qp  = qkvb + (size_t)(qvi * 3 + 0) * BHTD + hb;  // [t][d]
    const short* Kit = qkvb + (size_t)(kvi * 3 + 1) * BHTD + hb;  // [t][d], marches
    const short* V0it = qkvb + (size_t)(v0i * 3 + 2) * BHTD + hb; // [d][t], marches
    const short* V1it = qkvb + (size_t)(v1i * 3 + 2) * BHTD + hb;

    // fixed per-lane offsets (loop-invariant -> scalar base march)
    const int koffl = l16 * 64 + quad * 8;      // K: +32 (ch), +1024 (nt)
    const int voffl = l16 * NT + quad * 8;      // V: +16*NT per dt

    s8v qf[2][2];
#pragma unroll
    for (int mt = 0; mt < 2; ++mt)
#pragma unroll
        for (int ch = 0; ch < 2; ++ch)
            qf[mt][ch] = *(const s8v*)&Qp[(size_t)(q0 + 32 * wv + 16 * mt + l16) * 64 + ch * 32 + quad * 8];

    float lsum[2][4];
    f4 acc0[2][4], acc1[2][4];
#pragma unroll
    for (int mt = 0; mt < 2; ++mt)
#pragma unroll
        for (int r = 0; r < 4; ++r) lsum[mt][r] = 0.f;
#pragma unroll
    for (int mt = 0; mt < 2; ++mt)
#pragma unroll
        for (int i = 0; i < 4; ++i) { acc0[mt][i] = f4{0,0,0,0}; acc1[mt][i] = f4{0,0,0,0}; }

    const int myktn = 4 * qt + wv + 1;     // causal bound for THIS wave's rows

    for (int kt = 0; kt < myktn; ++kt, Kit += 32 * 64, V0it += 32, V1it += 32) {
        const int k0 = kt * 32;

        // ---- K fragments: direct global b128, fixed lane offset ----
        s8v kf[2][2];
        kf[0][0] = *(const s8v*)&Kit[koffl];
        kf[0][1] = *(const s8v*)&Kit[koffl + 32];
        kf[1][0] = *(const s8v*)&Kit[koffl + 1024];
        kf[1][1] = *(const s8v*)&Kit[koffl + 1056];

        // ---- S = Q K^T (Q pre-scaled by 1/8) ----
        f4 s[2][2];
#pragma unroll
        for (int mt = 0; mt < 2; ++mt) { s[mt][0] = f4{0,0,0,0}; s[mt][1] = f4{0,0,0,0}; }
#pragma unroll
        for (int nt = 0; nt < 2; ++nt)
#pragma unroll
            for (int ch = 0; ch < 2; ++ch) {
                s[0][nt] = __builtin_amdgcn_mfma_f32_16x16x32_bf16(qf[0][ch], kf[nt][ch], s[0][nt], 0, 0, 0);
                s[1][nt] = __builtin_amdgcn_mfma_f32_16x16x32_bf16(qf[1][ch], kf[nt][ch], s[1][nt], 0, 0, 0);
            }

        // ---- V fragments: issue early so latency overlaps exp ----
        s8v vf0[4], vf1[4];
#pragma unroll
        for (int dt = 0; dt < 4; ++dt)
            vf0[dt] = *(const s8v*)&V0it[voffl + dt * 16 * NT];
        if (two) {
#pragma unroll
            for (int dt = 0; dt < 4; ++dt)
                vf1[dt] = *(const s8v*)&V1it[voffl + dt * 16 * NT];
        }

        // ---- fixed-shift softmax: p = 2^(s*log2e - 28.85) ----
#pragma unroll
        for (int mt = 0; mt < 2; ++mt) {
            const int rowb = q0 + 32 * wv + 16 * mt;
            float a0[4], a1[4];
#pragma unroll
            for (int r = 0; r < 4; ++r) { a0[r] = s[mt][0][r]; a1[r] = s[mt][1][r]; }
            if (k0 + 31 > rowb) {          // causal mask (near-diagonal only)
#pragma unroll
                for (int r = 0; r < 4; ++r) {
                    const int row = rowb + quad * 4 + r;
                    if (k0 + l16 > row)      a0[r] = NEG;
                    if (k0 + 16 + l16 > row) a1[r] = NEG;
                }
            }
#pragma unroll
            for (int r = 0; r < 4; ++r) {
                const float p0 = fast_exp2(fmaf(a0[r], EXC1, EXC0));   // ->0 for masked
                const float p1 = fast_exp2(fmaf(a1[r], EXC1, EXC0));
                lsum[mt][r] += p0 + p1;
                Ps[(32 * wv + 16 * mt + quad * 4 + r) * 40 + l16]      = bfbits(p0);
                Ps[(32 * wv + 16 * mt + quad * 4 + r) * 40 + 16 + l16] = bfbits(p1);
            }
        }

        // ---- O += P V (P via LDS, wave-private rows: no barrier) ----
        const s8v pf0 = *(const s8v*)&Ps[(32 * wv + l16) * 40 + quad * 8];
        const s8v pf1 = *(const s8v*)&Ps[(32 * wv + 16 + l16) * 40 + quad * 8];
#pragma unroll
        for (int dt = 0; dt < 4; ++dt) {
            acc0[0][dt] = __builtin_amdgcn_mfma_f32_16x16x32_bf16(pf0, vf0[dt], acc0[0][dt], 0, 0, 0);
            acc0[1][dt] = __builtin_amdgcn_mfma_f32_16x16x32_bf16(pf1, vf0[dt], acc0[1][dt], 0, 0, 0);
            if (two) {
                acc1[0][dt] = __builtin_amdgcn_mfma_f32_16x16x32_bf16(pf0, vf1[dt], acc1[0][dt], 0, 0, 0);
                acc1[1][dt] = __builtin_amdgcn_mfma_f32_16x16x32_bf16(pf1, vf1[dt], acc1[1][dt], 0, 0, 0);
            }
        }
    }

#pragma unroll
    for (int mt = 0; mt < 2; ++mt) {
        float inv[4];
#pragma unroll
        for (int r = 0; r < 4; ++r) inv[r] = 1.f / red16sum(lsum[mt][r]);
#pragma unroll
        for (int dt = 0; dt < 4; ++dt)
#pragma unroll
            for (int r = 0; r < 4; ++r) {
                const size_t o = hb + (size_t)(q0 + 32 * wv + 16 * mt + quad * 4 + r) * 64 + dt * 16 + l16;
                if (!two) {
                    ybuf[o] = acc0[mt][dt][r] * inv[r];
                } else {
                    const float xa = acc0[mt][dt][r] * inv[r];
                    const float xb = acc1[mt][dt][r] * inv[r];
                    cand[(size_t)(sv - 1) * BHTD + o] = bfbits(fminf(xa, xb));
                    cand[(size_t)(3 + sv) * BHTD + o] = bfbits(fmaxf(xa, xb));
                }
            }
    }
}

// ---------------------------------------------------------------------------
// Kernel 3: MFMA output projection. z=0: A=y fp32; z=1: A=min of 4 candLo;
// z=2: A=max of 4 candHi. B=Wp (bf16). out fp32 via LDS re-layout.
// ---------------------------------------------------------------------------
__global__ __launch_bounds__(256) void out_proj_mfma(
    const float* __restrict__ ybuf, const short* __restrict__ cand,
    const float* __restrict__ Wp, float* __restrict__ out)
{
    __shared__ float smf[64 * 68];          // 17.4 KB; staging aliases first 10.2 KB
    short* As = (short*)smf;                // [64][40]
    short* Bs = As + 2560;
    float* Eb = smf;                        // [64][68]

    const int o  = blockIdx.z;
    const int j0 = blockIdx.x * 64, n0 = blockIdx.y * 64;
    const int t  = threadIdx.x;
    const int wv = t >> 6, lane = t & 63, quad = lane >> 4, l16 = lane & 15;
    const int rw = t >> 2, koff = (t & 3) * 8;

    f4 acc[4];
#pragma unroll
    for (int i = 0; i < 4; i++) acc[i] = f4{0,0,0,0};

    const int token = n0 + rw, b = token >> 11, tt = token & 2047;

    for (int k0 = 0; k0 < NC; k0 += 32) {
        const int hh = k0 >> 6, d0 = (k0 & 63) + koff;
        const size_t aoff = ((size_t)(b * 12 + hh) * NT + tt) * 64 + d0;
        s8v av;
        if (o == 0) {
            const f4 y0 = *(const f4*)&ybuf[aoff];
            const f4 y1 = *(const f4*)&ybuf[aoff + 4];
#pragma unroll
            for (int i = 0; i < 4; i++) { av[i] = bfbits(y0[i]); av[4 + i] = bfbits(y1[i]); }
        } else {
            const short* cb = cand + (size_t)(o == 1 ? 0 : 4) * BHTD;
            float v[8];
            {
                const s8v c0 = *(const s8v*)&cb[aoff];
#pragma unroll
                for (int i = 0; i < 8; i++) v[i] = bf2f(c0[i]);
            }
#pragma unroll
            for (int q = 1; q < 4; ++q) {
                const s8v cq = *(const s8v*)&cb[(size_t)q * BHTD + aoff];
                if (o == 1) {
#pragma unroll
                    for (int i = 0; i < 8; i++) v[i] = fminf(v[i], bf2f(cq[i]));
                } else {
#pragma unroll
                    for (int i = 0; i < 8; i++) v[i] = fmaxf(v[i], bf2f(cq[i]));
                }
            }
#pragma unroll
            for (int i = 0; i < 8; i++) av[i] = bfbits(v[i]);
        }
        const size_t wo = (size_t)(j0 + rw) * NC + k0 + koff;
        const f4 w0 = *(const f4*)&Wp[wo], w1 = *(const f4*)&Wp[wo + 4];
        s8v bv;
#pragma unroll
        for (int i = 0; i < 4; i++) { bv[i] = bfbits(w0[i]); bv[4 + i] = bfbits(w1[i]); }
        __syncthreads();
        *(s8v*)&As[rw * 40 + koff] = av;
        *(s8v*)&Bs[rw * 40 + koff] = bv;
        __syncthreads();
        const s8v af = *(const s8v*)&As[(wv * 16 + l16) * 40 + quad * 8];
#pragma unroll
        for (int nt = 0; nt < 4; ++nt) {
            const s8v bf = *(const s8v*)&Bs[(nt * 16 + l16) * 40 + quad * 8];
            acc[nt] = __builtin_amdgcn_mfma_f32_16x16x32_bf16(af, bf, acc[nt], 0, 0, 0);
        }
    }
    __syncthreads();
#pragma unroll
    for (int nt = 0; nt < 4; ++nt)
#pragma unroll
        for (int r = 0; r < 4; ++r)
            Eb[(wv * 16 + quad * 4 + r) * 68 + nt * 16 + l16] = acc[nt][r];
    __syncthreads();
    const int cc = (t & 3) * 16;
#pragma unroll
    for (int i = 0; i < 4; ++i) {
        const f4 vo = *(const f4*)&Eb[rw * 68 + cc + 4 * i];
        *(f4*)&out[(size_t)o * BTC + (size_t)(n0 + rw) * NC + j0 + cc + 4 * i] = vo;
    }
}

extern "C" void kernel_launch(void* const* d_in, const int* in_sizes, int n_in,
                              void* d_out, int out_size, void* d_ws, size_t ws_size,
                              hipStream_t stream)
{
    const float* x  = (const float*)d_in[0];
    const float* xl = (const float*)d_in[1];
    const float* xu = (const float*)d_in[2];
    const float* Wa = (const float*)d_in[3];
    const float* Wp = (const float*)d_in[4];
    float* out = (float*)d_out;

    short* qkvb = (short*)d_ws;                       // 9*BHTD bf16  = 56.6 MB
    float* ybuf = (float*)(qkvb + (size_t)9 * BHTD);  // 1*BHTD f32   = 12.6 MB
    short* cand = (short*)(ybuf + (size_t)BHTD);      // 8*BHTD bf16  = 50.3 MB

    qkv_proj_mfma <<<dim3(36, 64),    256, 0, stream>>>(x, xl, xu, Wa, qkvb);
    flash_mfma_all<<<dim3(16, 24, 5), 256, 0, stream>>>(qkvb, ybuf, cand);
    out_proj_mfma <<<dim3(12, 64, 3), 256, 0, stream>>>(ybuf, cand, Wp, out);
}

// Round 7
// 901.218 us; speedup vs baseline: 1.0626x; 1.0174x over previous
//
#include <hip/hip_runtime.h>
#include <hip/hip_bf16.h>
#include <cstdint>

typedef float f4  __attribute__((ext_vector_type(4)));
typedef short s8v __attribute__((ext_vector_type(8)));   // 8 bf16 (4 VGPRs)
typedef short s4v __attribute__((ext_vector_type(4)));   // 4 bf16 (2 VGPRs)
typedef int   i4v __attribute__((ext_vector_type(4)));

#define BHTD 3145728    // B*H*T*D = 2*12*2048*64
#define BTC  3145728
#define NT   2048
#define NC   768
#define NEG  -1e30f
// fixed-shift softmax: p = exp(s - 20) = 2^(s*log2e - 20*log2e)
#define EXC1 1.4426950408889634f
#define EXC0 -28.853900817779268f

static __device__ __forceinline__ short bfbits(float f) {
    return __builtin_bit_cast(short, __float2bfloat16(f));
}
static __device__ __forceinline__ float bf2f(short s) {
    return __builtin_bit_cast(float, (int)(((unsigned int)(unsigned short)s) << 16));
}
static __device__ __forceinline__ float fast_exp2(float x) {
    return __builtin_amdgcn_exp2f(x);    // v_exp_f32
}

// ---------------------------------------------------------------------------
// Kernel 1: MFMA QKV projection (unchanged from R6).
// Outputs bf16: Q (pre-scaled 1/8), K in [var][part][B,H,T,D]; V in [B,H,D,T].
// ---------------------------------------------------------------------------
__global__ __launch_bounds__(256) void qkv_proj_mfma(
    const float* __restrict__ x, const float* __restrict__ xl,
    const float* __restrict__ xu, const float* __restrict__ W,
    short* __restrict__ qkvb)
{
    __shared__ short sm[4 * 64 * 40];
    short* Ax = sm;
    short* Am = sm + 2560;
    short* Ar = sm + 5120;
    short* Bw = sm + 7680;
    short* Eb = sm;                     // epilogue [64][72]

    const int j0 = blockIdx.x * 64;
    const int n0 = blockIdx.y * 64;
    const int t  = threadIdx.x;
    const int wv = t >> 6, lane = t & 63, quad = lane >> 4, l16 = lane & 15;
    const int rw = t >> 2, koff = (t & 3) * 8;

    f4 aN[4], aM[4], aR[4];
#pragma unroll
    for (int i = 0; i < 4; i++) { aN[i] = f4{0,0,0,0}; aM[i] = f4{0,0,0,0}; aR[i] = f4{0,0,0,0}; }

    for (int k0 = 0; k0 < NC; k0 += 32) {
        const size_t xo = (size_t)(n0 + rw) * NC + k0 + koff;
        const f4 x0 = *(const f4*)&x[xo],  x1 = *(const f4*)&x[xo + 4];
        const f4 l0 = *(const f4*)&xl[xo], l1 = *(const f4*)&xl[xo + 4];
        const f4 u0 = *(const f4*)&xu[xo], u1 = *(const f4*)&xu[xo + 4];
        const size_t wo = (size_t)(j0 + rw) * NC + k0 + koff;
        const f4 w0 = *(const f4*)&W[wo], w1 = *(const f4*)&W[wo + 4];
        s8v vx, vm, vr, vw;
#pragma unroll
        for (int i = 0; i < 4; i++) {
            vx[i]     = bfbits(x0[i]);              vx[4 + i] = bfbits(x1[i]);
            vm[i]     = bfbits(0.5f * (l0[i] + u0[i])); vm[4 + i] = bfbits(0.5f * (l1[i] + u1[i]));
            vr[i]     = bfbits(0.5f * (u0[i] - l0[i])); vr[4 + i] = bfbits(0.5f * (u1[i] - l1[i]));
            vw[i]     = bfbits(w0[i]);              vw[4 + i] = bfbits(w1[i]);
        }
        __syncthreads();
        *(s8v*)&Ax[rw * 40 + koff] = vx;
        *(s8v*)&Am[rw * 40 + koff] = vm;
        *(s8v*)&Ar[rw * 40 + koff] = vr;
        *(s8v*)&Bw[rw * 40 + koff] = vw;
        __syncthreads();
        const s8v fx = *(const s8v*)&Ax[(wv * 16 + l16) * 40 + quad * 8];
        const s8v fm = *(const s8v*)&Am[(wv * 16 + l16) * 40 + quad * 8];
        const s8v fr = *(const s8v*)&Ar[(wv * 16 + l16) * 40 + quad * 8];
#pragma unroll
        for (int nt = 0; nt < 4; ++nt) {
            const s8v fb = *(const s8v*)&Bw[(nt * 16 + l16) * 40 + quad * 8];
            i4v bi = __builtin_bit_cast(i4v, fb);
#pragma unroll
            for (int i = 0; i < 4; i++) bi[i] &= 0x7fff7fff;
            const s8v fa = __builtin_bit_cast(s8v, bi);
            aN[nt] = __builtin_amdgcn_mfma_f32_16x16x32_bf16(fx, fb, aN[nt], 0, 0, 0);
            aM[nt] = __builtin_amdgcn_mfma_f32_16x16x32_bf16(fm, fb, aM[nt], 0, 0, 0);
            aR[nt] = __builtin_amdgcn_mfma_f32_16x16x32_bf16(fr, fa, aR[nt], 0, 0, 0);
        }
    }

    const int p = j0 / NC, hh = (j0 % NC) >> 6;
    const float qsc = (p == 0) ? 0.125f : 1.0f;
    const int cc16 = (t & 3) * 16;
    for (int var = 0; var < 3; ++var) {
        __syncthreads();
#pragma unroll
        for (int nt = 0; nt < 4; ++nt)
#pragma unroll
            for (int r = 0; r < 4; ++r) {
                const float v = ((var == 0) ? aN[nt][r]
                              : (var == 1) ? aM[nt][r] - aR[nt][r]
                                           : aM[nt][r] + aR[nt][r]) * qsc;
                Eb[(wv * 16 + quad * 4 + r) * 72 + nt * 16 + l16] = bfbits(v);
            }
        __syncthreads();
        short* dst = qkvb + (size_t)(var * 3 + p) * BHTD;
        if (p < 2) {
            const int token = n0 + rw, b = token >> 11, tt = token & 2047;
            const size_t o = ((size_t)(b * 12 + hh) * NT + tt) * 64 + cc16;
            *(s8v*)&dst[o]     = *(const s8v*)&Eb[rw * 72 + cc16];
            *(s8v*)&dst[o + 8] = *(const s8v*)&Eb[rw * 72 + cc16 + 8];
        } else {
            const int d = rw;
            s8v e0, e1;
#pragma unroll
            for (int i = 0; i < 8; i++) e0[i] = Eb[(cc16 + i) * 72 + d];
#pragma unroll
            for (int i = 0; i < 8; i++) e1[i] = Eb[(cc16 + 8 + i) * 72 + d];
            const int token0 = n0 + cc16, b = token0 >> 11, tt = token0 & 2047;
            const size_t o = ((size_t)(b * 12 + hh) * 64 + d) * NT + tt;
            *(s8v*)&dst[o]     = e0;
            *(s8v*)&dst[o + 8] = e1;
        }
    }
}

// ---------------------------------------------------------------------------
// Kernel 2: register-resident flash. Computes S^T = K·Q^T (operand swap) so
// the C-layout (row=k=quad*4+r, col=q=l16) IS the A-layout of the 16x16x16
// PV MFMA -> P never leaves registers. Zero LDS, zero barriers.
// Balanced pairing: block bx handles qt = 15-bx then qt = bx (uniform work).
// K prefetched one tile ahead; V loaded at iter top (b64 from V^T [d][t]).
// ---------------------------------------------------------------------------
__global__ __launch_bounds__(256, 3) void flash_mfma_all(
    const short* __restrict__ qkvb, float* __restrict__ ybuf,
    short* __restrict__ cand)
{
    const int bx = blockIdx.x;             // 0..7
    const int bh = blockIdx.y;
    const int sv = blockIdx.z;             // 0..4
    const int t  = threadIdx.x;
    const int wv = t >> 6, lane = t & 63, quad = lane >> 4, l16 = lane & 15;

    const bool two = (sv > 0);
    const int qvi = (sv + 1) >> 1;
    const int kvi = two ? 2 - (sv & 1) : 0;
    const int v0i = two ? 1 : 0;
    const int v1i = two ? 2 : 0;

    const size_t hb = (size_t)bh * (NT * 64);
    const short* Qp  = qkvb + (size_t)(qvi * 3 + 0) * BHTD + hb;  // [t][d]
    const short* Kp0 = qkvb + (size_t)(kvi * 3 + 1) * BHTD + hb;  // [t][d]
    const short* V0p = qkvb + (size_t)(v0i * 3 + 2) * BHTD + hb;  // [d][t]
    const short* V1p = qkvb + (size_t)(v1i * 3 + 2) * BHTD + hb;  // [d][t]

    const int koffl = l16 * 64 + quad * 8;     // K A-frag lane offset
    const int voffl = l16 * NT + quad * 4;     // V B-frag lane offset (+dt*16*NT +kt2*16)

    for (int ph = 0; ph < 2; ++ph) {
        const int qt  = ph ? bx : 15 - bx;
        const int q0w = qt * 128 + 32 * wv;    // this wave's 32 q-rows

        // Q fragments (B-operand of S^T): qf[qh][ch]
        s8v qf[2][2];
#pragma unroll
        for (int qh = 0; qh < 2; ++qh)
#pragma unroll
            for (int ch = 0; ch < 2; ++ch)
                qf[qh][ch] = *(const s8v*)&Qp[(size_t)(q0w + qh * 16 + l16) * 64 + ch * 32 + quad * 8];

        float lsum[2] = {0.f, 0.f};
        f4 acc0[2][4], acc1[2][4];
#pragma unroll
        for (int qh = 0; qh < 2; ++qh)
#pragma unroll
            for (int dt = 0; dt < 4; ++dt) { acc0[qh][dt] = f4{0,0,0,0}; acc1[qh][dt] = f4{0,0,0,0}; }

        const int myktn = 4 * qt + wv + 1;

        const short* Kit = Kp0;
        s8v kfc[2][2];                         // current K tile (prefetched)
        kfc[0][0] = *(const s8v*)&Kit[koffl];
        kfc[0][1] = *(const s8v*)&Kit[koffl + 32];
        kfc[1][0] = *(const s8v*)&Kit[koffl + 1024];
        kfc[1][1] = *(const s8v*)&Kit[koffl + 1056];

        for (int kt = 0; kt < myktn; ++kt) {
            const int k0 = kt * 32;

            // ---- V B-frags: b64 from V^T, issued first (latency window) ----
            s4v vf0[2][4], vf1[2][4];
#pragma unroll
            for (int kt2 = 0; kt2 < 2; ++kt2)
#pragma unroll
                for (int dt = 0; dt < 4; ++dt)
                    vf0[kt2][dt] = *(const s4v*)&V0p[voffl + dt * 16 * NT + k0 + kt2 * 16];
            if (two) {
#pragma unroll
                for (int kt2 = 0; kt2 < 2; ++kt2)
#pragma unroll
                    for (int dt = 0; dt < 4; ++dt)
                        vf1[kt2][dt] = *(const s4v*)&V1p[voffl + dt * 16 * NT + k0 + kt2 * 16];
            }

            // ---- S^T = K·Q^T : st[kt2][qh], C row=k_local, col=q_local ----
            f4 st[2][2];
#pragma unroll
            for (int kt2 = 0; kt2 < 2; ++kt2) { st[kt2][0] = f4{0,0,0,0}; st[kt2][1] = f4{0,0,0,0}; }
#pragma unroll
            for (int kt2 = 0; kt2 < 2; ++kt2)
#pragma unroll
                for (int ch = 0; ch < 2; ++ch) {
                    st[kt2][0] = __builtin_amdgcn_mfma_f32_16x16x32_bf16(kfc[kt2][ch], qf[0][ch], st[kt2][0], 0, 0, 0);
                    st[kt2][1] = __builtin_amdgcn_mfma_f32_16x16x32_bf16(kfc[kt2][ch], qf[1][ch], st[kt2][1], 0, 0, 0);
                }

            // ---- prefetch next K tile (always in-bounds within ws) ----
            Kit += 32 * 64;
            kfc[0][0] = *(const s8v*)&Kit[koffl];
            kfc[0][1] = *(const s8v*)&Kit[koffl + 32];
            kfc[1][0] = *(const s8v*)&Kit[koffl + 1024];
            kfc[1][1] = *(const s8v*)&Kit[koffl + 1056];

            // ---- fixed-shift exp, mask, pack into PV A-frags ----
            s4v pa[2][2];
#pragma unroll
            for (int kt2 = 0; kt2 < 2; ++kt2)
#pragma unroll
                for (int qh = 0; qh < 2; ++qh) {
                    const int rowb = q0w + qh * 16;        // min q of this tile
                    const bool msk = (k0 + kt2 * 16 + 15 > rowb);
#pragma unroll
                    for (int r = 0; r < 4; ++r) {
                        float v = st[kt2][qh][r];
                        if (msk && (k0 + kt2 * 16 + quad * 4 + r > rowb + l16)) v = NEG;
                        const float p = fast_exp2(fmaf(v, EXC1, EXC0));
                        lsum[qh] += p;
                        pa[kt2][qh][r] = bfbits(p);
                    }
                }

            // ---- O += P·V : 16x16x16, P from registers ----
#pragma unroll
            for (int kt2 = 0; kt2 < 2; ++kt2)
#pragma unroll
                for (int qh = 0; qh < 2; ++qh)
#pragma unroll
                    for (int dt = 0; dt < 4; ++dt) {
                        acc0[qh][dt] = __builtin_amdgcn_mfma_f32_16x16x16bf16_1k(
                            pa[kt2][qh], vf0[kt2][dt], acc0[qh][dt], 0, 0, 0);
                        if (two)
                            acc1[qh][dt] = __builtin_amdgcn_mfma_f32_16x16x16bf16_1k(
                                pa[kt2][qh], vf1[kt2][dt], acc1[qh][dt], 0, 0, 0);
                    }
        } // kt

        // ---- deferred l reduction + cross-lane inv broadcast ----
        float invq[2];
#pragma unroll
        for (int qh = 0; qh < 2; ++qh) {
            float s = lsum[qh];
            s += __shfl_xor(s, 16, 64);
            s += __shfl_xor(s, 32, 64);
            invq[qh] = 1.f / s;        // valid for q_local = qh*16 + l16, all lanes
        }

#pragma unroll
        for (int qh = 0; qh < 2; ++qh)
#pragma unroll
            for (int r = 0; r < 4; ++r) {
                const float inv = __shfl(invq[qh], quad * 4 + r, 64);
                const size_t o = hb + (size_t)(q0w + qh * 16 + quad * 4 + r) * 64 + l16;
#pragma unroll
                for (int dt = 0; dt < 4; ++dt) {
                    if (!two) {
                        ybuf[o + dt * 16] = acc0[qh][dt][r] * inv;
                    } else {
                        const float xa = acc0[qh][dt][r] * inv;
                        const float xb = acc1[qh][dt][r] * inv;
                        cand[(size_t)(sv - 1) * BHTD + o + dt * 16] = bfbits(fminf(xa, xb));
                        cand[(size_t)(3 + sv) * BHTD + o + dt * 16] = bfbits(fmaxf(xa, xb));
                    }
                }
            }
    } // ph
}

// ---------------------------------------------------------------------------
// Kernel 3: MFMA output projection (unchanged from R6).
// ---------------------------------------------------------------------------
__global__ __launch_bounds__(256) void out_proj_mfma(
    const float* __restrict__ ybuf, const short* __restrict__ cand,
    const float* __restrict__ Wp, float* __restrict__ out)
{
    __shared__ float smf[64 * 68];
    short* As = (short*)smf;
    short* Bs = As + 2560;
    float* Eb = smf;

    const int o  = blockIdx.z;
    const int j0 = blockIdx.x * 64, n0 = blockIdx.y * 64;
    const int t  = threadIdx.x;
    const int wv = t >> 6, lane = t & 63, quad = lane >> 4, l16 = lane & 15;
    const int rw = t >> 2, koff = (t & 3) * 8;

    f4 acc[4];
#pragma unroll
    for (int i = 0; i < 4; i++) acc[i] = f4{0,0,0,0};

    const int token = n0 + rw, b = token >> 11, tt = token & 2047;

    for (int k0 = 0; k0 < NC; k0 += 32) {
        const int hh = k0 >> 6, d0 = (k0 & 63) + koff;
        const size_t aoff = ((size_t)(b * 12 + hh) * NT + tt) * 64 + d0;
        s8v av;
        if (o == 0) {
            const f4 y0 = *(const f4*)&ybuf[aoff];
            const f4 y1 = *(const f4*)&ybuf[aoff + 4];
#pragma unroll
            for (int i = 0; i < 4; i++) { av[i] = bfbits(y0[i]); av[4 + i] = bfbits(y1[i]); }
        } else {
            const short* cb = cand + (size_t)(o == 1 ? 0 : 4) * BHTD;
            float v[8];
            {
                const s8v c0 = *(const s8v*)&cb[aoff];
#pragma unroll
                for (int i = 0; i < 8; i++) v[i] = bf2f(c0[i]);
            }
#pragma unroll
            for (int q = 1; q < 4; ++q) {
                const s8v cq = *(const s8v*)&cb[(size_t)q * BHTD + aoff];
                if (o == 1) {
#pragma unroll
                    for (int i = 0; i < 8; i++) v[i] = fminf(v[i], bf2f(cq[i]));
                } else {
#pragma unroll
                    for (int i = 0; i < 8; i++) v[i] = fmaxf(v[i], bf2f(cq[i]));
                }
            }
#pragma unroll
            for (int i = 0; i < 8; i++) av[i] = bfbits(v[i]);
        }
        const size_t wo = (size_t)(j0 + rw) * NC + k0 + koff;
        const f4 w0 = *(const f4*)&Wp[wo], w1 = *(const f4*)&Wp[wo + 4];
        s8v bv;
#pragma unroll
        for (int i = 0; i < 4; i++) { bv[i] = bfbits(w0[i]); bv[4 + i] = bfbits(w1[i]); }
        __syncthreads();
        *(s8v*)&As[rw * 40 + koff] = av;
        *(s8v*)&Bs[rw * 40 + koff] = bv;
        __syncthreads();
        const s8v af = *(const s8v*)&As[(wv * 16 + l16) * 40 + quad * 8];
#pragma unroll
        for (int nt = 0; nt < 4; ++nt) {
            const s8v bf = *(const s8v*)&Bs[(nt * 16 + l16) * 40 + quad * 8];
            acc[nt] = __builtin_amdgcn_mfma_f32_16x16x32_bf16(af, bf, acc[nt], 0, 0, 0);
        }
    }
    __syncthreads();
#pragma unroll
    for (int nt = 0; nt < 4; ++nt)
#pragma unroll
        for (int r = 0; r < 4; ++r)
            Eb[(wv * 16 + quad * 4 + r) * 68 + nt * 16 + l16] = acc[nt][r];
    __syncthreads();
    const int cc = (t & 3) * 16;
#pragma unroll
    for (int i = 0; i < 4; ++i) {
        const f4 vo = *(const f4*)&Eb[rw * 68 + cc + 4 * i];
        *(f4*)&out[(size_t)o * BTC + (size_t)(n0 + rw) * NC + j0 + cc + 4 * i] = vo;
    }
}

extern "C" void kernel_launch(void* const* d_in, const int* in_sizes, int n_in,
                              void* d_out, int out_size, void* d_ws, size_t ws_size,
                              hipStream_t stream)
{
    const float* x  = (const float*)d_in[0];
    const float* xl = (const float*)d_in[1];
    const float* xu = (const float*)d_in[2];
    const float* Wa = (const float*)d_in[3];
    const float* Wp = (const float*)d_in[4];
    float* out = (float*)d_out;

    short* qkvb = (short*)d_ws;                       // 9*BHTD bf16  = 56.6 MB
    float* ybuf = (float*)(qkvb + (size_t)9 * BHTD);  // 1*BHTD f32   = 12.6 MB
    short* cand = (short*)(ybuf + (size_t)BHTD);      // 8*BHTD bf16  = 50.3 MB

    qkv_proj_mfma <<<dim3(36, 64),    256, 0, stream>>>(x, xl, xu, Wa, qkvb);
    flash_mfma_all<<<dim3(8, 24, 5),  256, 0, stream>>>(qkvb, ybuf, cand);
    out_proj_mfma <<<dim3(12, 64, 3), 256, 0, stream>>>(ybuf, cand, Wp, out);
}